// Round 4
// baseline (198.755 us; speedup 1.0000x reference)
//
#include <hip/hip_runtime.h>

#define NROWS 384
#define DDIM  768
#define L2E2  2.885390081777927f   // 2*log2(e): exp(2s) = exp2(L2E2*s)

// ws floats: pTb [192 kg][384 i][4]  at 0        (p transposed, d-blocked)
//            A2  [384 i][768 d]      at 294912   (prescaled A'+b1, row-major, atomic-acc)
//            Bt2 [192 dg][384 j][4]  at 589824   (prescaled B, d-blocked, atomic-acc)
#define WS_A2 (NROWS * DDIM)
#define WS_BT (2 * NROWS * DDIM)
#define KSPLIT 4
#define KCHUNK (DDIM / KSPLIT)   // 192
#define DSPLIT 4
#define DCHUNK (DDIM / DSPLIT)   // 192

// ---------------------------------------------------------------------------
// K0: d-blocked transpose of p + zero the atomic-accumulation regions (ws
// A2/Bt2 and d_out) in spare blocks. 1152 blocks x 256 = 294912 float4 tasks.
// ---------------------------------------------------------------------------
__global__ __launch_bounds__(256) void k0_prep(
    const float* __restrict__ p, float* __restrict__ ws,
    float* __restrict__ out) {
  const int flat = blockIdx.x * 256 + threadIdx.x;
  const int NT  = NROWS * DDIM / 4;        // 73728 transpose tasks
  const int NZW = 2 * NROWS * DDIM / 4;    // 147456 ws-zero tasks
  if (flat < NT) {
    const int i  = flat / (DDIM / 4);
    const int kg = flat % (DDIM / 4);
    ((float4*)ws)[kg * NROWS + i] = ((const float4*)p)[flat];
  } else if (flat < NT + NZW) {
    ((float4*)(ws + WS_A2))[flat - NT] = make_float4(0.f, 0.f, 0.f, 0.f);
  } else {
    ((float4*)out)[flat - NT - NZW] = make_float4(0.f, 0.f, 0.f, 0.f);
  }
}

// ---------------------------------------------------------------------------
// K1: partial GEMM, k-split x4. wave -> 8 cols c (W1 rows wave-uniform ->
// s_load), lane -> 64 i rows (coalesced float4 pTb). 32 FMA per vector load.
// Partials (prescaled by L2E2, b1 folded by chunk 0) atomically accumulated:
// A half row-major, B half d-blocked.
// grid (48, 6, 4): x = col-block/32, y = row-block/64, z = k-chunk.
// ---------------------------------------------------------------------------
__global__ __launch_bounds__(256) void k1_gemm(
    const float* __restrict__ ws_in, const float* __restrict__ W1,
    const float* __restrict__ b1, float* __restrict__ ws) {
  const int lane = threadIdx.x & 63;
  const int wave = threadIdx.x >> 6;
  const int row  = blockIdx.y * 64 + lane;
  const int kc   = blockIdx.z;
  const int c0   = __builtin_amdgcn_readfirstlane(blockIdx.x * 32 + wave * 8);
  const int g    = c0 >= DDIM;          // 0 = A half, 1 = B half
  const int o0   = c0 - g * DDIM;       // W1 row base in [0,768)

  const float4* __restrict__ pT4 = (const float4*)ws_in;
  const float*  __restrict__ wb  =
      W1 + (size_t)o0 * (2 * DDIM) + g * DDIM + kc * KCHUNK;

  float acc[8] = {};

  #pragma unroll 2
  for (int kg = 0; kg < KCHUNK / 4; ++kg) {
    const float4 pv = pT4[(kc * (KCHUNK / 4) + kg) * NROWS + row];  // coalesced
    #pragma unroll
    for (int cc = 0; cc < 8; ++cc) {
      const float4 w4 = *(const float4*)&wb[(size_t)cc * (2 * DDIM) + 4 * kg];  // s_load
      acc[cc] = fmaf(pv.x, w4.x, acc[cc]);
      acc[cc] = fmaf(pv.y, w4.y, acc[cc]);
      acc[cc] = fmaf(pv.z, w4.z, acc[cc]);
      acc[cc] = fmaf(pv.w, w4.w, acc[cc]);
    }
  }

  if (g == 0) {
    float* A2 = ws + WS_A2;   // row-major [384][768]
    #pragma unroll
    for (int cc = 0; cc < 8; ++cc) {
      float v = acc[cc];
      if (kc == 0) v += b1[o0 + cc];
      unsafeAtomicAdd(&A2[(size_t)row * DDIM + o0 + cc], v * L2E2);
    }
  } else {
    float* Bt = ws + WS_BT;   // d-blocked [192][384][4]
    #pragma unroll
    for (int cc = 0; cc < 8; ++cc) {
      const int o = o0 + cc;
      unsafeAtomicAdd(&Bt[((size_t)(o >> 2) * NROWS + row) * 4 + (o & 3)],
                      acc[cc] * L2E2);
    }
  }
}

// ---------------------------------------------------------------------------
// K2: d-split x4. out[i][j][c] += sumW_dc - 2*sum_{d in chunk} W2[c][d]*r
//     with r = rcp(exp2(A2[i][d] + Bt2[j][d]) + 1); chunk 0 also adds b2.
// wave -> 1 i row (uniform sequential s_loads of A2/W2), lane -> j
// (coalesced Bt2 float4, L1-shared by the block's 4 waves).
// grid (96, 6, 4): x = i-group of 4 waves, y = j-block, z = d-chunk.
// ---------------------------------------------------------------------------
__global__ __launch_bounds__(256) void k2_fused(
    const float* __restrict__ ws, const float* __restrict__ W2,
    const float* __restrict__ b2, float* __restrict__ out) {
  const int lane = threadIdx.x & 63;
  const int wave = threadIdx.x >> 6;
  const int i  = __builtin_amdgcn_readfirstlane(blockIdx.x * 4 + wave);
  const int j  = blockIdx.y * 64 + lane;
  const int dc = blockIdx.z;

  const float*  __restrict__ Ai = ws + WS_A2 + (size_t)i * DDIM + dc * DCHUNK;
  const float4* __restrict__ B4 =
      (const float4*)(ws + WS_BT) + (size_t)dc * (DCHUNK / 4) * NROWS;
  const float*  __restrict__ w0 = W2 + dc * DCHUNK;
  const float*  __restrict__ w1 = W2 + DDIM + dc * DCHUNK;

  // chunk-partial sumW (wave-uniform after butterfly)
  float sw0 = 0.f, sw1 = 0.f;
  #pragma unroll
  for (int d = 0; d < DCHUNK; d += 64) { sw0 += w0[d + lane]; sw1 += w1[d + lane]; }
  #pragma unroll
  for (int off = 32; off; off >>= 1) {
    sw0 += __shfl_xor(sw0, off);
    sw1 += __shfl_xor(sw1, off);
  }

  float s0[4] = {}, s1[4] = {};

  #pragma unroll 4
  for (int dg = 0; dg < DCHUNK / 4; ++dg) {
    const float4 b4  = B4[dg * NROWS + j];            // coalesced per-lane
    const float4 a4  = *(const float4*)&Ai[dg * 4];   // uniform sequential
    const float4 w04 = *(const float4*)&w0[dg * 4];
    const float4 w14 = *(const float4*)&w1[dg * 4];

    float e, r;
    e = __builtin_amdgcn_exp2f(a4.x + b4.x); r = __builtin_amdgcn_rcpf(e + 1.f);
    s0[0] = fmaf(w04.x, r, s0[0]); s1[0] = fmaf(w14.x, r, s1[0]);
    e = __builtin_amdgcn_exp2f(a4.y + b4.y); r = __builtin_amdgcn_rcpf(e + 1.f);
    s0[1] = fmaf(w04.y, r, s0[1]); s1[1] = fmaf(w14.y, r, s1[1]);
    e = __builtin_amdgcn_exp2f(a4.z + b4.z); r = __builtin_amdgcn_rcpf(e + 1.f);
    s0[2] = fmaf(w04.z, r, s0[2]); s1[2] = fmaf(w14.z, r, s1[2]);
    e = __builtin_amdgcn_exp2f(a4.w + b4.w); r = __builtin_amdgcn_rcpf(e + 1.f);
    s0[3] = fmaf(w04.w, r, s0[3]); s1[3] = fmaf(w14.w, r, s1[3]);
  }

  const float S0 = (s0[0] + s0[1]) + (s0[2] + s0[3]);
  const float S1 = (s1[0] + s1[1]) + (s1[2] + s1[3]);
  float r0 = fmaf(-2.f, S0, sw0);
  float r1 = fmaf(-2.f, S1, sw1);
  if (dc == 0) { r0 += b2[0]; r1 += b2[1]; }
  float* o = &out[((size_t)i * NROWS + j) * 2];
  unsafeAtomicAdd(o + 0, r0);
  unsafeAtomicAdd(o + 1, r1);
}

// ---------------------------------------------------------------------------
extern "C" void kernel_launch(void* const* d_in, const int* in_sizes, int n_in,
                              void* d_out, int out_size, void* d_ws, size_t ws_size,
                              hipStream_t stream) {
  const float* p  = (const float*)d_in[0];   // [384, 768]
  const float* W1 = (const float*)d_in[1];   // [768, 1536]
  const float* b1 = (const float*)d_in[2];   // [768]
  const float* W2 = (const float*)d_in[3];   // [2, 768]
  const float* b2 = (const float*)d_in[4];   // [2]
  float* out = (float*)d_out;                // [384, 384, 2]
  float* ws  = (float*)d_ws;                 // 884736 floats (3.4 MB)

  k0_prep<<<dim3(1152), 256, 0, stream>>>(p, ws, out);

  dim3 g1(2 * DDIM / 32, NROWS / 64, KSPLIT);   // 48 x 6 x 4
  k1_gemm<<<g1, 256, 0, stream>>>(ws, W1, b1, ws);

  dim3 g2(NROWS / 4, NROWS / 64, DSPLIT);       // 96 x 6 x 4
  k2_fused<<<g2, 256, 0, stream>>>(ws, W2, b2, out);
}

// Round 5
// 179.671 us; speedup vs baseline: 1.1062x; 1.1062x over previous
//
#include <hip/hip_runtime.h>
#include <stdint.h>

#define NROWS 384
#define DDIM  768
#define NCOL  1536
#define L2E2  2.885390081777927f   // 2*log2(e): exp(2s) = exp2(L2E2*s)

// ws floats: A2  [384 i][768 d]     at 0        (prescaled (A+b1)*L2E2, row-major)
//            Bt2 [192 dg][384 j][4] at 294912   (prescaled B*L2E2, d-blocked)
// total 589824 floats = 2.36 MB (proven-safe ws size)
#define WS_BT (NROWS * DDIM)

typedef short bf16x8 __attribute__((ext_vector_type(8)));
typedef float f32x4  __attribute__((ext_vector_type(4)));

__device__ __forceinline__ uint16_t f2bf(float x) {  // RNE float->bf16
  const uint32_t u = __float_as_uint(x);
  return (uint16_t)((u + 0x7FFFu + ((u >> 16) & 1u)) >> 16);
}

__device__ __forceinline__ bf16x8 pack8(const float* f) {
  bf16x8 r;
  #pragma unroll
  for (int j = 0; j < 8; ++j) r[j] = (short)f2bf(f[j]);
  return r;
}

// ---------------------------------------------------------------------------
// K1: C[i][o] = sum_k p[i][k] * W1[o%768][ (o>=768)*768 + k ],  o in [0,1536)
// One wave per block; wave computes a 16(m) x 64(n) tile with 4x
// mfma_f32_16x16x32_bf16 per k-step (24 steps). fp32 inputs converted to bf16
// in-register (RNE). Epilogue folds b1 (A half) and the L2E2 prescale, stores
// A half row-major and B half d-blocked. No LDS, no atomics.
// A/B frag layout: lane&15 = m (or n), (lane>>4)*8+j = k (8 contiguous).
// C/D layout (verified m89/m91): col = lane&15, row = (lane>>4)*4 + reg.
// ---------------------------------------------------------------------------
__global__ __launch_bounds__(64) void k1_mfma(
    const float* __restrict__ p, const float* __restrict__ W1,
    const float* __restrict__ b1, float* __restrict__ ws) {
  const int lane  = threadIdx.x;
  const int nn    = lane & 15;
  const int quad  = lane >> 4;
  const int nbase = blockIdx.x * 64;   // 0..1472
  const int mbase = blockIdx.y * 16;   // 0..368
  const int g     = (nbase >= DDIM);   // wave-uniform half select

  f32x4 acc[4] = {{0,0,0,0},{0,0,0,0},{0,0,0,0},{0,0,0,0}};

  const float* __restrict__ pa = p + (size_t)(mbase + nn) * DDIM + quad * 8;
  const int obase = nbase - g * DDIM;  // W1 row base in [0,768)

  for (int k0 = 0; k0 < DDIM; k0 += 32) {
    float af[8];
    *(float4*)&af[0] = *(const float4*)&pa[k0];
    *(float4*)&af[4] = *(const float4*)&pa[k0 + 4];
    const bf16x8 a = pack8(af);
    #pragma unroll
    for (int c = 0; c < 4; ++c) {
      const float* __restrict__ pb =
          W1 + (size_t)(obase + c * 16 + nn) * NCOL + g * DDIM + k0 + quad * 8;
      float bf[8];
      *(float4*)&bf[0] = *(const float4*)&pb[0];
      *(float4*)&bf[4] = *(const float4*)&pb[4];
      acc[c] = __builtin_amdgcn_mfma_f32_16x16x32_bf16(a, pack8(bf), acc[c], 0, 0, 0);
    }
  }

  if (g == 0) {
    float* __restrict__ A2 = ws;       // row-major [384][768]
    #pragma unroll
    for (int c = 0; c < 4; ++c) {
      const int o = nbase + c * 16 + nn;
      const float bias = b1[o];
      #pragma unroll
      for (int r = 0; r < 4; ++r) {
        const int i = mbase + quad * 4 + r;
        A2[(size_t)i * DDIM + o] = (acc[c][r] + bias) * L2E2;
      }
    }
  } else {
    float* __restrict__ Bt = ws + WS_BT;  // d-blocked [192][384][4]
    #pragma unroll
    for (int c = 0; c < 4; ++c) {
      const int od = obase + c * 16 + nn;
      const int hi = (od >> 2) * NROWS;
      const int lo = od & 3;
      #pragma unroll
      for (int r = 0; r < 4; ++r) {
        const int i = mbase + quad * 4 + r;
        Bt[(size_t)(hi + i) * 4 + lo] = acc[c][r] * L2E2;
      }
    }
  }
}

// ---------------------------------------------------------------------------
// K2: logits[i][j][c] = (sumW_c - 2*sum_d W2[c][d]*r_ijd) + b2[c],
//     r = rcp(exp2(A2[i][d] + Bt2[j][d]) + 1)   (prescale folded in K1)
// Block = 512 threads = 8 waves = 4 i-rows x 2 d-halves; per-lane partials of
// partner waves combined through LDS (no atomics). lane -> j (coalesced Bt2
// float4); A2/W2 rows wave-uniform (scalar pipe). 4608 waves = 4.5/SIMD.
// ---------------------------------------------------------------------------
__global__ __launch_bounds__(512) void k2_fused(
    const float* __restrict__ ws, const float* __restrict__ W2,
    const float* __restrict__ b2, float* __restrict__ out) {
  __shared__ float part[4][64][2];

  const int lane = threadIdx.x & 63;
  const int w    = threadIdx.x >> 6;   // 0..7
  const int h    = w >> 2;             // d-half
  const int iw   = w & 3;
  const int i    = __builtin_amdgcn_readfirstlane(blockIdx.x * 4 + iw);
  const int j    = blockIdx.y * 64 + lane;

  const float*  __restrict__ Ai = ws + (size_t)i * DDIM + h * 384;
  const float4* __restrict__ B4 = (const float4*)(ws + WS_BT) + (size_t)h * 96 * NROWS;
  const float*  __restrict__ w0 = W2 + h * 384;
  const float*  __restrict__ w1 = W2 + DDIM + h * 384;

  // half-chunk sumW (wave-uniform after butterfly)
  float sw0 = 0.f, sw1 = 0.f;
  #pragma unroll
  for (int d = 0; d < 384; d += 64) { sw0 += w0[d + lane]; sw1 += w1[d + lane]; }
  #pragma unroll
  for (int off = 32; off; off >>= 1) {
    sw0 += __shfl_xor(sw0, off);
    sw1 += __shfl_xor(sw1, off);
  }

  float s0[4] = {}, s1[4] = {};

  #pragma unroll 4
  for (int dg = 0; dg < 96; ++dg) {
    const float4 b4  = B4[dg * NROWS + j];            // coalesced per-lane
    const float4 a4  = *(const float4*)&Ai[dg * 4];   // uniform
    const float4 w04 = *(const float4*)&w0[dg * 4];
    const float4 w14 = *(const float4*)&w1[dg * 4];

    float e, r;
    e = __builtin_amdgcn_exp2f(a4.x + b4.x); r = __builtin_amdgcn_rcpf(e + 1.f);
    s0[0] = fmaf(w04.x, r, s0[0]); s1[0] = fmaf(w14.x, r, s1[0]);
    e = __builtin_amdgcn_exp2f(a4.y + b4.y); r = __builtin_amdgcn_rcpf(e + 1.f);
    s0[1] = fmaf(w04.y, r, s0[1]); s1[1] = fmaf(w14.y, r, s1[1]);
    e = __builtin_amdgcn_exp2f(a4.z + b4.z); r = __builtin_amdgcn_rcpf(e + 1.f);
    s0[2] = fmaf(w04.z, r, s0[2]); s1[2] = fmaf(w14.z, r, s1[2]);
    e = __builtin_amdgcn_exp2f(a4.w + b4.w); r = __builtin_amdgcn_rcpf(e + 1.f);
    s0[3] = fmaf(w04.w, r, s0[3]); s1[3] = fmaf(w14.w, r, s1[3]);
  }

  const float S0 = (s0[0] + s0[1]) + (s0[2] + s0[3]);
  const float S1 = (s1[0] + s1[1]) + (s1[2] + s1[3]);
  const float p0 = fmaf(-2.f, S0, sw0);   // half-chunk partial logit
  const float p1 = fmaf(-2.f, S1, sw1);

  if (h) { part[iw][lane][0] = p0; part[iw][lane][1] = p1; }
  __syncthreads();
  if (!h) {
    float2 r2;
    r2.x = p0 + part[iw][lane][0] + b2[0];
    r2.y = p1 + part[iw][lane][1] + b2[1];
    *(float2*)&out[((size_t)i * NROWS + j) * 2] = r2;
  }
}

// ---------------------------------------------------------------------------
extern "C" void kernel_launch(void* const* d_in, const int* in_sizes, int n_in,
                              void* d_out, int out_size, void* d_ws, size_t ws_size,
                              hipStream_t stream) {
  const float* p  = (const float*)d_in[0];   // [384, 768]
  const float* W1 = (const float*)d_in[1];   // [768, 1536]
  const float* b1 = (const float*)d_in[2];   // [768]
  const float* W2 = (const float*)d_in[3];   // [2, 768]
  const float* b2 = (const float*)d_in[4];   // [2]
  float* out = (float*)d_out;                // [384, 384, 2]
  float* ws  = (float*)d_ws;                 // 589824 floats (2.36 MB)

  dim3 g1(NCOL / 64, NROWS / 16);            // 24 x 24, one wave per block
  k1_mfma<<<g1, 64, 0, stream>>>(p, W1, b1, ws);

  dim3 g2(NROWS / 4, NROWS / 64);            // 96 x 6, 512-thread blocks
  k2_fused<<<g2, 512, 0, stream>>>(ws, W2, b2, out);
}

// Round 6
// 123.883 us; speedup vs baseline: 1.6044x; 1.4503x over previous
//
#include <hip/hip_runtime.h>
#include <stdint.h>

#define NROWS 384
#define DDIM  768
#define NCOL  1536
#define L2E2  2.885390081777927f   // 2*log2(e): exp(2s) = exp2(L2E2*s)

// ws floats: A2  [384 i][768 d]     at 0        (prescaled (A+b1)*L2E2, row-major)
//            Bt2 [192 dg][384 j][4] at 294912   (prescaled B*L2E2, d-blocked)
#define WS_BT (NROWS * DDIM)

typedef short bf16x8 __attribute__((ext_vector_type(8)));
typedef float f32x4  __attribute__((ext_vector_type(4)));

__device__ __forceinline__ uint16_t f2bf(float x) {  // RNE float->bf16
  const uint32_t u = __float_as_uint(x);
  return (uint16_t)((u + 0x7FFFu + ((u >> 16) & 1u)) >> 16);
}
__device__ __forceinline__ bf16x8 pack8(const float* f) {
  bf16x8 r;
  #pragma unroll
  for (int j = 0; j < 8; ++j) r[j] = (short)f2bf(f[j]);
  return r;
}

// ---------------------------------------------------------------------------
// K1: C[i][o] = sum_k p[i][k] * W1[o%768][(o>=768)*768 + k], MFMA bf16.
// Block = 256 thr = 4 waves = 2 n-subtiles x 2 k-halves (in-block k-split,
// LDS combine, no atomics). Each wave: one 16x16 tile over 384 k (12 iters,
// unroll 4 -> 16 loads in flight). Grid 48x24 = 1152 blocks = 4.5 waves/SIMD.
// Epilogue folds b1 (A half) + L2E2 prescale; A2 row-major, Bt2 d-blocked.
// ---------------------------------------------------------------------------
__global__ __launch_bounds__(256) void k1_mfma(
    const float* __restrict__ p, const float* __restrict__ W1,
    const float* __restrict__ b1, float* __restrict__ ws) {
  __shared__ float cmb[2][64][4];

  const int lane = threadIdx.x & 63;
  const int w    = threadIdx.x >> 6;
  const int nsub = w & 1;
  const int ksub = w >> 1;
  const int nn   = lane & 15;
  const int quad = lane >> 4;

  const int mbase = blockIdx.y * 16;
  const int nbase = blockIdx.x * 32 + nsub * 16;   // [0,1536)
  const int g     = nbase >= DDIM;                 // block-uniform half
  const int obase = nbase - g * DDIM;              // W1 row base [0,768)

  const float* __restrict__ pa =
      p + (size_t)(mbase + nn) * DDIM + ksub * 384 + quad * 8;
  const float* __restrict__ pb =
      W1 + (size_t)(obase + nn) * NCOL + g * DDIM + ksub * 384 + quad * 8;

  f32x4 acc = {0.f, 0.f, 0.f, 0.f};

  #pragma unroll 4
  for (int kk = 0; kk < 384; kk += 32) {
    float af[8], bf_[8];
    *(float4*)&af[0]  = *(const float4*)&pa[kk];
    *(float4*)&af[4]  = *(const float4*)&pa[kk + 4];
    *(float4*)&bf_[0] = *(const float4*)&pb[kk];
    *(float4*)&bf_[4] = *(const float4*)&pb[kk + 4];
    acc = __builtin_amdgcn_mfma_f32_16x16x32_bf16(pack8(af), pack8(bf_), acc, 0, 0, 0);
  }

  if (ksub == 1)
    *(float4*)&cmb[nsub][lane][0] = make_float4(acc[0], acc[1], acc[2], acc[3]);
  __syncthreads();
  if (ksub == 0) {
    const float4 o4 = *(const float4*)&cmb[nsub][lane][0];
    float v[4] = {acc[0] + o4.x, acc[1] + o4.y, acc[2] + o4.z, acc[3] + o4.w};
    const int od = obase + nn;
    if (!g) {
      const float bias = b1[od];
      float* __restrict__ A2 = ws;
      #pragma unroll
      for (int r = 0; r < 4; ++r)
        A2[(size_t)(mbase + quad * 4 + r) * DDIM + od] = (v[r] + bias) * L2E2;
    } else {
      float* __restrict__ Bt = ws + WS_BT;
      const int hi = (od >> 2) * NROWS;
      const int lo = od & 3;
      #pragma unroll
      for (int r = 0; r < 4; ++r)
        Bt[(size_t)(hi + mbase + quad * 4 + r) * 4 + lo] = v[r] * L2E2;
    }
  }
}

// ---------------------------------------------------------------------------
// K2: logits[i][j][c] = (sumW_c - 2*sum_d W2[c][d]*r_ijd) + b2[c],
//     r = rcp(exp2(A2[i][d] + Bt2[j][d]) + 1)   (prescale folded in K1)
// Block = 256 thr = 4 waves = 4 d-quarters of one i-pair; all wave-uniform
// operands (A rows, W2) staged in LDS (interleaved, ds_read_b128 — no SMEM
// K$-miss stalls in the loop). lane -> j, b4 coalesced. Quarter-partials
// combined via LDS. Grid (192,6) = 1152 blocks = 4.5 waves/SIMD, balanced.
// ---------------------------------------------------------------------------
__global__ __launch_bounds__(256) void k2_fused(
    const float* __restrict__ ws, const float* __restrict__ W2,
    const float* __restrict__ b2, float* __restrict__ out) {
  __shared__ float As[192][8];    // [dg][ i0:d0..3 | i1:d0..3 ]
  __shared__ float Wsh[192][8];   // [dg][ c0:d0..3 | c1:d0..3 ]
  __shared__ float part[3][2][64][2];

  const int lane = threadIdx.x & 63;
  const int h    = threadIdx.x >> 6;        // d-quarter 0..3
  const int i0   = blockIdx.x * 2;
  const int i1   = i0 + 1;
  const int j    = blockIdx.y * 64 + lane;

  // stage A-row pair + W2 into LDS (interleaved), coalesced float4 reads
  for (int u = threadIdx.x; u < 768; u += 256) {
    if (u < 384) {
      const int dg = u >> 1, which = u & 1;
      *(float4*)&As[dg][which * 4] =
          *(const float4*)&ws[(size_t)(i0 + which) * DDIM + dg * 4];
    } else {
      const int v = u - 384, dg = v >> 1, which = v & 1;
      *(float4*)&Wsh[dg][which * 4] =
          *(const float4*)&W2[(size_t)which * DDIM + dg * 4];
    }
  }

  // quarter-range sumW (wave-uniform after butterfly)
  const float* __restrict__ w0g = W2 + h * 192;
  const float* __restrict__ w1g = W2 + DDIM + h * 192;
  float sw0 = w0g[lane] + w0g[lane + 64] + w0g[lane + 128];
  float sw1 = w1g[lane] + w1g[lane + 64] + w1g[lane + 128];
  #pragma unroll
  for (int off = 32; off; off >>= 1) {
    sw0 += __shfl_xor(sw0, off);
    sw1 += __shfl_xor(sw1, off);
  }
  __syncthreads();

  const float4* __restrict__ B4 =
      (const float4*)(ws + WS_BT) + (size_t)(h * 48) * NROWS + j;

  float4 a00 = {0,0,0,0}, a01 = {0,0,0,0}, a10 = {0,0,0,0}, a11 = {0,0,0,0};

  #pragma unroll 4
  for (int dg = 0; dg < 48; ++dg) {
    const int dgg = h * 48 + dg;
    const float4 b4  = B4[(size_t)dg * NROWS];          // coalesced per-lane
    const float4 av0 = *(const float4*)&As[dgg][0];     // LDS broadcast
    const float4 av1 = *(const float4*)&As[dgg][4];
    const float4 w04 = *(const float4*)&Wsh[dgg][0];
    const float4 w14 = *(const float4*)&Wsh[dgg][4];

    float e, r;
    e = __builtin_amdgcn_exp2f(av0.x + b4.x); r = __builtin_amdgcn_rcpf(e + 1.f);
    a00.x = fmaf(w04.x, r, a00.x); a01.x = fmaf(w14.x, r, a01.x);
    e = __builtin_amdgcn_exp2f(av1.x + b4.x); r = __builtin_amdgcn_rcpf(e + 1.f);
    a10.x = fmaf(w04.x, r, a10.x); a11.x = fmaf(w14.x, r, a11.x);

    e = __builtin_amdgcn_exp2f(av0.y + b4.y); r = __builtin_amdgcn_rcpf(e + 1.f);
    a00.y = fmaf(w04.y, r, a00.y); a01.y = fmaf(w14.y, r, a01.y);
    e = __builtin_amdgcn_exp2f(av1.y + b4.y); r = __builtin_amdgcn_rcpf(e + 1.f);
    a10.y = fmaf(w04.y, r, a10.y); a11.y = fmaf(w14.y, r, a11.y);

    e = __builtin_amdgcn_exp2f(av0.z + b4.z); r = __builtin_amdgcn_rcpf(e + 1.f);
    a00.z = fmaf(w04.z, r, a00.z); a01.z = fmaf(w14.z, r, a01.z);
    e = __builtin_amdgcn_exp2f(av1.z + b4.z); r = __builtin_amdgcn_rcpf(e + 1.f);
    a10.z = fmaf(w04.z, r, a10.z); a11.z = fmaf(w14.z, r, a11.z);

    e = __builtin_amdgcn_exp2f(av0.w + b4.w); r = __builtin_amdgcn_rcpf(e + 1.f);
    a00.w = fmaf(w04.w, r, a00.w); a01.w = fmaf(w14.w, r, a01.w);
    e = __builtin_amdgcn_exp2f(av1.w + b4.w); r = __builtin_amdgcn_rcpf(e + 1.f);
    a10.w = fmaf(w04.w, r, a10.w); a11.w = fmaf(w14.w, r, a11.w);
  }

  const float S00 = (a00.x + a00.y) + (a00.z + a00.w);
  const float S01 = (a01.x + a01.y) + (a01.z + a01.w);
  const float S10 = (a10.x + a10.y) + (a10.z + a10.w);
  const float S11 = (a11.x + a11.y) + (a11.z + a11.w);
  const float p00 = fmaf(-2.f, S00, sw0);
  const float p01 = fmaf(-2.f, S01, sw1);
  const float p10 = fmaf(-2.f, S10, sw0);
  const float p11 = fmaf(-2.f, S11, sw1);

  if (h) {
    part[h - 1][0][lane][0] = p00; part[h - 1][0][lane][1] = p01;
    part[h - 1][1][lane][0] = p10; part[h - 1][1][lane][1] = p11;
  }
  __syncthreads();
  if (!h) {
    float2 r0, r1;
    r0.x = p00 + part[0][0][lane][0] + part[1][0][lane][0] + part[2][0][lane][0] + b2[0];
    r0.y = p01 + part[0][0][lane][1] + part[1][0][lane][1] + part[2][0][lane][1] + b2[1];
    r1.x = p10 + part[0][1][lane][0] + part[1][1][lane][0] + part[2][1][lane][0] + b2[0];
    r1.y = p11 + part[0][1][lane][1] + part[1][1][lane][1] + part[2][1][lane][1] + b2[1];
    *(float2*)&out[((size_t)i0 * NROWS + j) * 2] = r0;
    *(float2*)&out[((size_t)i1 * NROWS + j) * 2] = r1;
  }
}

// ---------------------------------------------------------------------------
extern "C" void kernel_launch(void* const* d_in, const int* in_sizes, int n_in,
                              void* d_out, int out_size, void* d_ws, size_t ws_size,
                              hipStream_t stream) {
  const float* p  = (const float*)d_in[0];   // [384, 768]
  const float* W1 = (const float*)d_in[1];   // [768, 1536]
  const float* b1 = (const float*)d_in[2];   // [768]
  const float* W2 = (const float*)d_in[3];   // [2, 768]
  const float* b2 = (const float*)d_in[4];   // [2]
  float* out = (float*)d_out;                // [384, 384, 2]
  float* ws  = (float*)d_ws;                 // 2.36 MB

  dim3 g1(NCOL / 32, NROWS / 16);            // 48 x 24 = 1152 blocks
  k1_mfma<<<g1, 256, 0, stream>>>(p, W1, b1, ws);

  dim3 g2(NROWS / 2, NROWS / 64);            // 192 x 6 = 1152 blocks
  k2_fused<<<g2, 256, 0, stream>>>(ws, W2, b2, out);
}

// Round 7
// 117.933 us; speedup vs baseline: 1.6853x; 1.0505x over previous
//
#include <hip/hip_runtime.h>
#include <stdint.h>

#define NROWS 384
#define DDIM  768
#define NCOL  1536
#define L2E2  2.885390081777927f   // 2*log2(e): exp(2s) = exp2(L2E2*s)

// ws regions (float-slot offsets):
//   A2   [384 i][768 d]  fp32 at 0        (prescaled (A+b1)*L2E2, row-major)
//   Bt2  [192 dg][384 j][4] fp32 at 294912 (prescaled B*L2E2, d-blocked)
//   pbf  [384 i][768 k]  bf16 at 589824   (p converted once)
//   wbf  [768 o][1536 c] bf16 at 737280   (W1 converted once)
#define WS_BT  294912
#define WS_PBF 589824
#define WS_WBF 737280

typedef short bf16x8 __attribute__((ext_vector_type(8)));
typedef float f32x4  __attribute__((ext_vector_type(4)));

__device__ __forceinline__ uint16_t f2bf(float x) {  // RNE float->bf16
  const uint32_t u = __float_as_uint(x);
  return (uint16_t)((u + 0x7FFFu + ((u >> 16) & 1u)) >> 16);
}
__device__ __forceinline__ bf16x8 pack8(const float* f) {
  bf16x8 r;
  #pragma unroll
  for (int j = 0; j < 8; ++j) r[j] = (short)f2bf(f[j]);
  return r;
}

// ---------------------------------------------------------------------------
// K0: one-time fp32->bf16 conversion of p and W1 (layouts preserved).
// 184320 thread-tasks of 8 elems (2x float4 in, 16B out), 720 blocks.
// Removes all per-fragment pack VALU from k1's inner loop.
// ---------------------------------------------------------------------------
__global__ __launch_bounds__(256) void k0_cvt(
    const float* __restrict__ p, const float* __restrict__ W1,
    float* __restrict__ ws) {
  const int t = blockIdx.x * 256 + threadIdx.x;
  const int NP = NROWS * DDIM / 8;          // 36864 p-tasks
  float f[8];
  if (t < NP) {
    *(float4*)&f[0] = *(const float4*)&p[t * 8];
    *(float4*)&f[4] = *(const float4*)&p[t * 8 + 4];
    *(bf16x8*)((uint16_t*)(ws + WS_PBF) + (size_t)t * 8) = pack8(f);
  } else {
    const int u = t - NP;                   // 147456 W1-tasks
    *(float4*)&f[0] = *(const float4*)&W1[(size_t)u * 8];
    *(float4*)&f[4] = *(const float4*)&W1[(size_t)u * 8 + 4];
    *(bf16x8*)((uint16_t*)(ws + WS_WBF) + (size_t)u * 8) = pack8(f);
  }
}

// ---------------------------------------------------------------------------
// K1: C[i][o] = sum_k p[i][k] * W1[o%768][(o>=768)*768 + k], MFMA bf16.
// Fragments loaded directly as bf16 (16B loads, L2-resident) — no pack VALU.
// Block = 256 thr = 4 waves = 2 n-subtiles x 2 k-halves (LDS combine).
// Grid 48x24 = 1152 blocks. Epilogue folds b1 + L2E2; A2 row-major, Bt2
// d-blocked.
// ---------------------------------------------------------------------------
__global__ __launch_bounds__(256) void k1_mfma(
    const float* __restrict__ b1, float* __restrict__ ws) {
  __shared__ float cmb[2][64][4];

  const int lane = threadIdx.x & 63;
  const int w    = threadIdx.x >> 6;
  const int nsub = w & 1;
  const int ksub = w >> 1;
  const int nn   = lane & 15;
  const int quad = lane >> 4;

  const int mbase = blockIdx.y * 16;
  const int nbase = blockIdx.x * 32 + nsub * 16;   // [0,1536)
  const int g     = nbase >= DDIM;
  const int obase = nbase - g * DDIM;              // W1 row base [0,768)

  const uint16_t* __restrict__ pbf = (const uint16_t*)(ws + WS_PBF);
  const uint16_t* __restrict__ wbf = (const uint16_t*)(ws + WS_WBF);

  const uint16_t* __restrict__ pa =
      pbf + (size_t)(mbase + nn) * DDIM + ksub * 384 + quad * 8;
  const uint16_t* __restrict__ pb =
      wbf + (size_t)(obase + nn) * NCOL + g * DDIM + ksub * 384 + quad * 8;

  f32x4 acc = {0.f, 0.f, 0.f, 0.f};

  #pragma unroll 4
  for (int kk = 0; kk < 384; kk += 32) {
    const bf16x8 a = *(const bf16x8*)&pa[kk];
    const bf16x8 b = *(const bf16x8*)&pb[kk];
    acc = __builtin_amdgcn_mfma_f32_16x16x32_bf16(a, b, acc, 0, 0, 0);
  }

  if (ksub == 1)
    *(float4*)&cmb[nsub][lane][0] = make_float4(acc[0], acc[1], acc[2], acc[3]);
  __syncthreads();
  if (ksub == 0) {
    const float4 o4 = *(const float4*)&cmb[nsub][lane][0];
    float v[4] = {acc[0] + o4.x, acc[1] + o4.y, acc[2] + o4.z, acc[3] + o4.w};
    const int od = obase + nn;
    if (!g) {
      const float bias = b1[od];
      float* __restrict__ A2 = ws;
      #pragma unroll
      for (int r = 0; r < 4; ++r)
        A2[(size_t)(mbase + quad * 4 + r) * DDIM + od] = (v[r] + bias) * L2E2;
    } else {
      float* __restrict__ Bt = ws + WS_BT;
      const int hi = (od >> 2) * NROWS;
      const int lo = od & 3;
      #pragma unroll
      for (int r = 0; r < 4; ++r)
        Bt[(size_t)(hi + mbase + quad * 4 + r) * 4 + lo] = v[r] * L2E2;
    }
  }
}

// ---------------------------------------------------------------------------
// K2: logits[i][j][c] = (sumW_c - 2*sum_d W2[c][d]*r_ijd) + b2[c],
//     r = rcp(exp2(A2[i][d] + Bt2[j][d]) + 1)   (prescale folded in K1)
// Block = 256 thr = 4 waves (d-quarters) x [4 i-rows x 64 j]. A-quad + W2
// staged in LDS interleaved [dg][row][4] (broadcast ds_read_b128). lane -> j,
// b4 coalesced and amortized over 4 i-rows; 16 independent exp chains/iter.
// Quarter-partials combined via LDS. Grid (96,6) = 576 blocks.
// ---------------------------------------------------------------------------
__global__ __launch_bounds__(256) void k2_fused(
    const float* __restrict__ ws, const float* __restrict__ W2,
    const float* __restrict__ b2, float* __restrict__ out) {
  __shared__ float As[192][16];    // [dg][row 0..3][d 0..3]
  __shared__ float Wsh[192][8];    // [dg][c 0..1][d 0..3]
  __shared__ float part[3][4][64][2];

  const int lane = threadIdx.x & 63;
  const int h    = threadIdx.x >> 6;        // d-quarter 0..3
  const int i0   = blockIdx.x * 4;
  const int j    = blockIdx.y * 64 + lane;

  // stage A-row quad + W2 into LDS (coalesced float4 reads)
  for (int u = threadIdx.x; u < 768 + 384; u += 256) {
    if (u < 768) {
      const int row = u / 192, dg = u % 192;
      *(float4*)&As[dg][row * 4] =
          *(const float4*)&ws[(size_t)(i0 + row) * DDIM + dg * 4];
    } else {
      const int v = u - 768, c = v / 192, dg = v % 192;
      *(float4*)&Wsh[dg][c * 4] =
          *(const float4*)&W2[(size_t)c * DDIM + dg * 4];
    }
  }

  // quarter-range sumW (wave-uniform after butterfly)
  const float* __restrict__ w0g = W2 + h * 192;
  const float* __restrict__ w1g = W2 + DDIM + h * 192;
  float sw0 = w0g[lane] + w0g[lane + 64] + w0g[lane + 128];
  float sw1 = w1g[lane] + w1g[lane + 64] + w1g[lane + 128];
  #pragma unroll
  for (int off = 32; off; off >>= 1) {
    sw0 += __shfl_xor(sw0, off);
    sw1 += __shfl_xor(sw1, off);
  }
  __syncthreads();

  const float4* __restrict__ B4 =
      (const float4*)(ws + WS_BT) + (size_t)(h * 48) * NROWS + j;

  f32x4 s0[4] = {{0,0,0,0},{0,0,0,0},{0,0,0,0},{0,0,0,0}};  // [row] c=0
  f32x4 s1[4] = {{0,0,0,0},{0,0,0,0},{0,0,0,0},{0,0,0,0}};  // [row] c=1

  #pragma unroll 2
  for (int dg = 0; dg < 48; ++dg) {
    const int dgg = h * 48 + dg;
    const float4 b4  = B4[(size_t)dg * NROWS];         // coalesced per-lane
    const float4 w04 = *(const float4*)&Wsh[dgg][0];   // LDS broadcast
    const float4 w14 = *(const float4*)&Wsh[dgg][4];

    #pragma unroll
    for (int row = 0; row < 4; ++row) {
      const float4 av = *(const float4*)&As[dgg][row * 4];
      float e, r;
      e = __builtin_amdgcn_exp2f(av.x + b4.x); r = __builtin_amdgcn_rcpf(e + 1.f);
      s0[row][0] = fmaf(w04.x, r, s0[row][0]); s1[row][0] = fmaf(w14.x, r, s1[row][0]);
      e = __builtin_amdgcn_exp2f(av.y + b4.y); r = __builtin_amdgcn_rcpf(e + 1.f);
      s0[row][1] = fmaf(w04.y, r, s0[row][1]); s1[row][1] = fmaf(w14.y, r, s1[row][1]);
      e = __builtin_amdgcn_exp2f(av.z + b4.z); r = __builtin_amdgcn_rcpf(e + 1.f);
      s0[row][2] = fmaf(w04.z, r, s0[row][2]); s1[row][2] = fmaf(w14.z, r, s1[row][2]);
      e = __builtin_amdgcn_exp2f(av.w + b4.w); r = __builtin_amdgcn_rcpf(e + 1.f);
      s0[row][3] = fmaf(w04.w, r, s0[row][3]); s1[row][3] = fmaf(w14.w, r, s1[row][3]);
    }
  }

  float p0[4], p1[4];
  #pragma unroll
  for (int row = 0; row < 4; ++row) {
    const float S0 = (s0[row][0] + s0[row][1]) + (s0[row][2] + s0[row][3]);
    const float S1 = (s1[row][0] + s1[row][1]) + (s1[row][2] + s1[row][3]);
    p0[row] = fmaf(-2.f, S0, sw0);
    p1[row] = fmaf(-2.f, S1, sw1);
  }

  if (h) {
    #pragma unroll
    for (int row = 0; row < 4; ++row) {
      part[h - 1][row][lane][0] = p0[row];
      part[h - 1][row][lane][1] = p1[row];
    }
  }
  __syncthreads();
  if (!h) {
    #pragma unroll
    for (int row = 0; row < 4; ++row) {
      float2 r2;
      r2.x = p0[row] + part[0][row][lane][0] + part[1][row][lane][0] +
             part[2][row][lane][0] + b2[0];
      r2.y = p1[row] + part[0][row][lane][1] + part[1][row][lane][1] +
             part[2][row][lane][1] + b2[1];
      *(float2*)&out[((size_t)(i0 + row) * NROWS + j) * 2] = r2;
    }
  }
}

// ---------------------------------------------------------------------------
extern "C" void kernel_launch(void* const* d_in, const int* in_sizes, int n_in,
                              void* d_out, int out_size, void* d_ws, size_t ws_size,
                              hipStream_t stream) {
  const float* p  = (const float*)d_in[0];   // [384, 768]
  const float* W1 = (const float*)d_in[1];   // [768, 1536]
  const float* b1 = (const float*)d_in[2];   // [768]
  const float* W2 = (const float*)d_in[3];   // [2, 768]
  const float* b2 = (const float*)d_in[4];   // [2]
  float* out = (float*)d_out;                // [384, 384, 2]
  float* ws  = (float*)d_ws;                 // ~5.3 MB used

  k0_cvt<<<dim3(720), 256, 0, stream>>>(p, W1, ws);

  dim3 g1(NCOL / 32, NROWS / 16);            // 48 x 24 = 1152 blocks
  k1_mfma<<<g1, 256, 0, stream>>>(b1, ws);

  dim3 g2(NROWS / 4, NROWS / 64);            // 96 x 6 = 576 blocks
  k2_fused<<<g2, 256, 0, stream>>>(ws, W2, b2, out);
}

// Round 8
// 112.428 us; speedup vs baseline: 1.7678x; 1.0490x over previous
//
#include <hip/hip_runtime.h>
#include <stdint.h>

#define NROWS 384
#define DDIM  768
#define NCOL  1536
#define L2E2  2.885390081777927f   // 2*log2(e): exp(2s) = exp2(L2E2*s)

// ws regions (float-slot offsets):
//   A2   [384 i][768 d]  fp32 at 0        (prescaled (A+b1)*L2E2, row-major)
//   Bt2  [192 dg][384 j][4] fp32 at 294912 (prescaled B*L2E2, d-blocked)
//   pbf  [384 i][768 k]  bf16 at 589824   (p converted once)
//   wbf  [768 o][1536 c] bf16 at 737280   (W1 converted once)
#define WS_BT  294912
#define WS_PBF 589824
#define WS_WBF 737280

typedef short bf16x8 __attribute__((ext_vector_type(8)));
typedef float f32x4  __attribute__((ext_vector_type(4)));

__device__ __forceinline__ uint16_t f2bf(float x) {  // RNE float->bf16
  const uint32_t u = __float_as_uint(x);
  return (uint16_t)((u + 0x7FFFu + ((u >> 16) & 1u)) >> 16);
}
__device__ __forceinline__ bf16x8 pack8(const float* f) {
  bf16x8 r;
  #pragma unroll
  for (int j = 0; j < 8; ++j) r[j] = (short)f2bf(f[j]);
  return r;
}

// ---------------------------------------------------------------------------
// K0: one-time fp32->bf16 conversion of p and W1 (layouts preserved).
// ---------------------------------------------------------------------------
__global__ __launch_bounds__(256) void k0_cvt(
    const float* __restrict__ p, const float* __restrict__ W1,
    float* __restrict__ ws) {
  const int t = blockIdx.x * 256 + threadIdx.x;
  const int NP = NROWS * DDIM / 8;          // 36864 p-tasks
  float f[8];
  if (t < NP) {
    *(float4*)&f[0] = *(const float4*)&p[t * 8];
    *(float4*)&f[4] = *(const float4*)&p[t * 8 + 4];
    *(bf16x8*)((uint16_t*)(ws + WS_PBF) + (size_t)t * 8) = pack8(f);
  } else {
    const int u = t - NP;                   // 147456 W1-tasks
    *(float4*)&f[0] = *(const float4*)&W1[(size_t)u * 8];
    *(float4*)&f[4] = *(const float4*)&W1[(size_t)u * 8 + 4];
    *(bf16x8*)((uint16_t*)(ws + WS_WBF) + (size_t)u * 8) = pack8(f);
  }
}

// ---------------------------------------------------------------------------
// K1: C[i][o] = sum_k p[i][k] * W1[o%768][(o>=768)*768 + k], MFMA bf16.
// Fragments loaded directly as bf16 (16B loads, L2-resident) — no pack VALU.
// Block = 256 thr = 4 waves = 2 n-subtiles x 2 k-halves (LDS combine).
// Grid 48x24 = 1152 blocks. Epilogue folds b1 + L2E2; A2 row-major, Bt2
// d-blocked.
// ---------------------------------------------------------------------------
__global__ __launch_bounds__(256) void k1_mfma(
    const float* __restrict__ b1, float* __restrict__ ws) {
  __shared__ float cmb[2][64][4];

  const int lane = threadIdx.x & 63;
  const int w    = threadIdx.x >> 6;
  const int nsub = w & 1;
  const int ksub = w >> 1;
  const int nn   = lane & 15;
  const int quad = lane >> 4;

  const int mbase = blockIdx.y * 16;
  const int nbase = blockIdx.x * 32 + nsub * 16;   // [0,1536)
  const int g     = nbase >= DDIM;
  const int obase = nbase - g * DDIM;              // W1 row base [0,768)

  const uint16_t* __restrict__ pbf = (const uint16_t*)(ws + WS_PBF);
  const uint16_t* __restrict__ wbf = (const uint16_t*)(ws + WS_WBF);

  const uint16_t* __restrict__ pa =
      pbf + (size_t)(mbase + nn) * DDIM + ksub * 384 + quad * 8;
  const uint16_t* __restrict__ pb =
      wbf + (size_t)(obase + nn) * NCOL + g * DDIM + ksub * 384 + quad * 8;

  f32x4 acc = {0.f, 0.f, 0.f, 0.f};

  #pragma unroll 4
  for (int kk = 0; kk < 384; kk += 32) {
    const bf16x8 a = *(const bf16x8*)&pa[kk];
    const bf16x8 b = *(const bf16x8*)&pb[kk];
    acc = __builtin_amdgcn_mfma_f32_16x16x32_bf16(a, b, acc, 0, 0, 0);
  }

  if (ksub == 1)
    *(float4*)&cmb[nsub][lane][0] = make_float4(acc[0], acc[1], acc[2], acc[3]);
  __syncthreads();
  if (ksub == 0) {
    const float4 o4 = *(const float4*)&cmb[nsub][lane][0];
    float v[4] = {acc[0] + o4.x, acc[1] + o4.y, acc[2] + o4.z, acc[3] + o4.w};
    const int od = obase + nn;
    if (!g) {
      const float bias = b1[od];
      float* __restrict__ A2 = ws;
      #pragma unroll
      for (int r = 0; r < 4; ++r)
        A2[(size_t)(mbase + quad * 4 + r) * DDIM + od] = (v[r] + bias) * L2E2;
    } else {
      float* __restrict__ Bt = ws + WS_BT;
      const int hi = (od >> 2) * NROWS;
      const int lo = od & 3;
      #pragma unroll
      for (int r = 0; r < 4; ++r)
        Bt[(size_t)(hi + mbase + quad * 4 + r) * 4 + lo] = v[r] * L2E2;
    }
  }
}

// ---------------------------------------------------------------------------
// K2: logits[i][j][c] = (sumW_c - 2*sum_d W2[c][d]*r_ijd) + b2[c],
//     r = rcp(exp2(A2[i][d] + Bt2[j][d]) + 1)   (prescale folded in K1)
// Block = 256 thr = 4 waves (d-quarters) x [2 i-rows x 64 j]. Grid (192,6) =
// 1152 blocks -> 4.5 waves/SIMD (TLP hides b4/LDS latency; per-SIMD VALU work
// is occupancy-invariant). A-pair + W2 staged in LDS, rows padded to 12
// floats (bank step 12 mod 32 -> 8 bank-groups, kills the 16-way staging
// conflict). lane -> j, b4 coalesced. Quarter-partials combined via LDS.
// ---------------------------------------------------------------------------
__global__ __launch_bounds__(256) void k2_fused(
    const float* __restrict__ ws, const float* __restrict__ W2,
    const float* __restrict__ b2, float* __restrict__ out) {
  __shared__ float As[192][12];    // [dg][row 0..1][d 0..3], cols 8..11 pad
  __shared__ float Wsh[192][12];   // [dg][c 0..1][d 0..3],  cols 8..11 pad
  __shared__ float part[3][2][64][2];

  const int lane = threadIdx.x & 63;
  const int h    = threadIdx.x >> 6;        // d-quarter 0..3
  const int i0   = blockIdx.x * 2;
  const int j    = blockIdx.y * 64 + lane;

  // stage A-row pair + W2 into LDS (coalesced float4 source reads)
  for (int u = threadIdx.x; u < 768; u += 256) {
    if (u < 384) {
      const int row = u / 192, dg = u % 192;
      *(float4*)&As[dg][row * 4] =
          *(const float4*)&ws[(size_t)(i0 + row) * DDIM + dg * 4];
    } else {
      const int v = u - 384, c = v / 192, dg = v % 192;
      *(float4*)&Wsh[dg][c * 4] =
          *(const float4*)&W2[(size_t)c * DDIM + dg * 4];
    }
  }

  // quarter-range sumW (wave-uniform after butterfly)
  const float* __restrict__ w0g = W2 + h * 192;
  const float* __restrict__ w1g = W2 + DDIM + h * 192;
  float sw0 = w0g[lane] + w0g[lane + 64] + w0g[lane + 128];
  float sw1 = w1g[lane] + w1g[lane + 64] + w1g[lane + 128];
  #pragma unroll
  for (int off = 32; off; off >>= 1) {
    sw0 += __shfl_xor(sw0, off);
    sw1 += __shfl_xor(sw1, off);
  }
  __syncthreads();

  const float4* __restrict__ B4 =
      (const float4*)(ws + WS_BT) + (size_t)(h * 48) * NROWS + j;

  f32x4 s00 = {0,0,0,0}, s01 = {0,0,0,0};   // row0: c0, c1
  f32x4 s10 = {0,0,0,0}, s11 = {0,0,0,0};   // row1: c0, c1

  #pragma unroll 2
  for (int dg = 0; dg < 48; ++dg) {
    const int dgg = h * 48 + dg;
    const float4 b4  = B4[(size_t)dg * NROWS];         // coalesced per-lane
    const float4 av0 = *(const float4*)&As[dgg][0];    // LDS broadcast
    const float4 av1 = *(const float4*)&As[dgg][4];
    const float4 w04 = *(const float4*)&Wsh[dgg][0];
    const float4 w14 = *(const float4*)&Wsh[dgg][4];

    float e, r;
    e = __builtin_amdgcn_exp2f(av0.x + b4.x); r = __builtin_amdgcn_rcpf(e + 1.f);
    s00[0] = fmaf(w04.x, r, s00[0]); s01[0] = fmaf(w14.x, r, s01[0]);
    e = __builtin_amdgcn_exp2f(av1.x + b4.x); r = __builtin_amdgcn_rcpf(e + 1.f);
    s10[0] = fmaf(w04.x, r, s10[0]); s11[0] = fmaf(w14.x, r, s11[0]);

    e = __builtin_amdgcn_exp2f(av0.y + b4.y); r = __builtin_amdgcn_rcpf(e + 1.f);
    s00[1] = fmaf(w04.y, r, s00[1]); s01[1] = fmaf(w14.y, r, s01[1]);
    e = __builtin_amdgcn_exp2f(av1.y + b4.y); r = __builtin_amdgcn_rcpf(e + 1.f);
    s10[1] = fmaf(w04.y, r, s10[1]); s11[1] = fmaf(w14.y, r, s11[1]);

    e = __builtin_amdgcn_exp2f(av0.z + b4.z); r = __builtin_amdgcn_rcpf(e + 1.f);
    s00[2] = fmaf(w04.z, r, s00[2]); s01[2] = fmaf(w14.z, r, s01[2]);
    e = __builtin_amdgcn_exp2f(av1.z + b4.z); r = __builtin_amdgcn_rcpf(e + 1.f);
    s10[2] = fmaf(w04.z, r, s10[2]); s11[2] = fmaf(w14.z, r, s11[2]);

    e = __builtin_amdgcn_exp2f(av0.w + b4.w); r = __builtin_amdgcn_rcpf(e + 1.f);
    s00[3] = fmaf(w04.w, r, s00[3]); s01[3] = fmaf(w14.w, r, s01[3]);
    e = __builtin_amdgcn_exp2f(av1.w + b4.w); r = __builtin_amdgcn_rcpf(e + 1.f);
    s10[3] = fmaf(w04.w, r, s10[3]); s11[3] = fmaf(w14.w, r, s11[3]);
  }

  const float S00 = (s00[0] + s00[1]) + (s00[2] + s00[3]);
  const float S01 = (s01[0] + s01[1]) + (s01[2] + s01[3]);
  const float S10 = (s10[0] + s10[1]) + (s10[2] + s10[3]);
  const float S11 = (s11[0] + s11[1]) + (s11[2] + s11[3]);
  const float p00 = fmaf(-2.f, S00, sw0);
  const float p01 = fmaf(-2.f, S01, sw1);
  const float p10 = fmaf(-2.f, S10, sw0);
  const float p11 = fmaf(-2.f, S11, sw1);

  if (h) {
    part[h - 1][0][lane][0] = p00; part[h - 1][0][lane][1] = p01;
    part[h - 1][1][lane][0] = p10; part[h - 1][1][lane][1] = p11;
  }
  __syncthreads();
  if (!h) {
    float2 r0, r1;
    r0.x = p00 + part[0][0][lane][0] + part[1][0][lane][0] + part[2][0][lane][0] + b2[0];
    r0.y = p01 + part[0][0][lane][1] + part[1][0][lane][1] + part[2][0][lane][1] + b2[1];
    r1.x = p10 + part[0][1][lane][0] + part[1][1][lane][0] + part[2][1][lane][0] + b2[0];
    r1.y = p11 + part[0][1][lane][1] + part[1][1][lane][1] + part[2][1][lane][1] + b2[1];
    *(float2*)&out[((size_t)i0 * NROWS + j) * 2] = r0;
    *(float2*)&out[((size_t)(i0 + 1) * NROWS + j) * 2] = r1;
  }
}

// ---------------------------------------------------------------------------
extern "C" void kernel_launch(void* const* d_in, const int* in_sizes, int n_in,
                              void* d_out, int out_size, void* d_ws, size_t ws_size,
                              hipStream_t stream) {
  const float* p  = (const float*)d_in[0];   // [384, 768]
  const float* W1 = (const float*)d_in[1];   // [768, 1536]
  const float* b1 = (const float*)d_in[2];   // [768]
  const float* W2 = (const float*)d_in[3];   // [2, 768]
  const float* b2 = (const float*)d_in[4];   // [2]
  float* out = (float*)d_out;                // [384, 384, 2]
  float* ws  = (float*)d_ws;                 // ~5.3 MB used

  k0_cvt<<<dim3(720), 256, 0, stream>>>(p, W1, ws);

  dim3 g1(NCOL / 32, NROWS / 16);            // 48 x 24 = 1152 blocks
  k1_mfma<<<g1, 256, 0, stream>>>(b1, ws);

  dim3 g2(NROWS / 2, NROWS / 64);            // 192 x 6 = 1152 blocks
  k2_fused<<<g2, 256, 0, stream>>>(ws, W2, b2, out);
}